// Round 2
// baseline (801.514 us; speedup 1.0000x reference)
//
#include <hip/hip_runtime.h>
#include <cstdint>

constexpr int D_S     = 256;    // scalar features (relu)
constexpr int D_G     = 384;    // gates (sigmoid)
constexpr int IN_ROW  = 2048;   // input row elements (fp32)
constexpr int OUT_ROW = 1664;   // output row elements (fp32)
constexpr int NS1_IN  = 640;    // input offset of ns1 block (768 elems, gate idx k/3)
constexpr int NS2_IN  = 1408;   // input offset of ns2 block (640 elems, gate idx 256+k/5)
constexpr int NS1_OUT = 256;
constexpr int NS2_OUT = 1024;
constexpr int ROWS    = 2;      // rows per block
constexpr int BLOCK   = 256;
constexpr int OUT_VECS = OUT_ROW / 4;         // 416 float4 vectors per output row
constexpr int TOTAL    = ROWS * OUT_VECS;     // 832 vectors per block

__global__ __launch_bounds__(BLOCK) void gated_block_parity_kernel(
        const float* __restrict__ in, float* __restrict__ out) {
    __shared__ float gl[ROWS * D_G];   // sigmoid(gates) for this block's rows
    const int tid = threadIdx.x;
    const long long row0 = (long long)blockIdx.x * ROWS;

    // ---- Phase 1: gates -> sigmoid -> LDS. ROWS*D_G = 768 floats = 192 x float4
    if (tid < 192) {
        const int r = tid / 96;              // 96 float4 gate vectors per row
        const int c = (tid - r * 96) * 4;
        const float4 v = *(const float4*)(in + (row0 + r) * IN_ROW + D_S + c);
        gl[r * D_G + c + 0] = 1.0f / (1.0f + __expf(-v.x));
        gl[r * D_G + c + 1] = 1.0f / (1.0f + __expf(-v.y));
        gl[r * D_G + c + 2] = 1.0f / (1.0f + __expf(-v.z));
        gl[r * D_G + c + 3] = 1.0f / (1.0f + __expf(-v.w));
    }
    __syncthreads();

    // ---- Phase 2: 832 float4 output vectors over 256 threads
    #pragma unroll
    for (int it = 0; it < (TOTAL + BLOCK - 1) / BLOCK; ++it) {
        const int v = tid + it * BLOCK;
        if (v >= TOTAL) break;
        const int r = v / OUT_VECS;
        const int o = (v - r * OUT_VECS) * 4;        // output element offset in row
        const long long in_base  = (row0 + r) * IN_ROW;
        const long long out_base = (row0 + r) * OUT_ROW;
        float4 d, res;
        if (o < D_S) {
            d = *(const float4*)(in + in_base + o);
            res.x = fmaxf(d.x, 0.0f);
            res.y = fmaxf(d.y, 0.0f);
            res.z = fmaxf(d.z, 0.0f);
            res.w = fmaxf(d.w, 0.0f);
        } else if (o < NS2_OUT) {
            const int k = o - NS1_OUT;               // 0..767, gate idx = k/3
            d = *(const float4*)(in + in_base + NS1_IN + k);
            const float* g = gl + r * D_G;
            res.x = d.x * g[(k + 0) / 3];
            res.y = d.y * g[(k + 1) / 3];
            res.z = d.z * g[(k + 2) / 3];
            res.w = d.w * g[(k + 3) / 3];
        } else {
            const int k = o - NS2_OUT;               // 0..639, gate idx = 256 + k/5
            d = *(const float4*)(in + in_base + NS2_IN + k);
            const float* g = gl + r * D_G + 256;
            res.x = d.x * g[(k + 0) / 5];
            res.y = d.y * g[(k + 1) / 5];
            res.z = d.z * g[(k + 2) / 5];
            res.w = d.w * g[(k + 3) / 5];
        }
        *(float4*)(out + out_base + o) = res;
    }
}

extern "C" void kernel_launch(void* const* d_in, const int* in_sizes, int n_in,
                              void* d_out, int out_size, void* d_ws, size_t ws_size,
                              hipStream_t stream) {
    const float* in  = (const float*)d_in[0];
    float*       out = (float*)d_out;
    const int rows = in_sizes[0] / IN_ROW;   // 65536
    const int grid = rows / ROWS;            // 32768 blocks
    hipLaunchKernelGGL(gated_block_parity_kernel, dim3(grid), dim3(BLOCK), 0, stream,
                       in, out);
}